// Round 3
// baseline (733.204 us; speedup 1.0000x reference)
//
#include <hip/hip_runtime.h>
#include <math.h>

// Batched Cholesky-OMP. X: [1024, B] f32, D: [1024, 1024] f32.
// out: [B*8] indices-as-float, then [B*8] coeffs.
// ws: G (1024*1024 f32) @ 0, h_bar (B*1024 f32) after it.

#define DIM    1024
#define NATOM  1024
#define SPAR   8
#define DIAG_EPS 1e-4f
#define CHOL_EPS 1e-6f

__device__ __forceinline__ float n2nf(float x) {
    return isfinite(x) ? x : 0.0f;
}

// ---------------- G = D^T D + eps*I ----------------
// 64x64 tile, BK=32, 256 threads, 4x4 micro-tile.
__global__ __launch_bounds__(256) void gram_kernel(const float* __restrict__ Dm,
                                                   float* __restrict__ G) {
    __shared__ float As[32][64];
    __shared__ float Bs[32][64];
    const int tid = threadIdx.x;
    const int tx = tid & 15, ty = tid >> 4;
    const int i0 = blockIdx.x * 64, j0 = blockIdx.y * 64;
    float acc[4][4] = {};
    for (int d0 = 0; d0 < DIM; d0 += 32) {
        #pragma unroll
        for (int l = 0; l < 2; ++l) {
            int f = tid + l * 256;          // 512 float4 per tile
            int r = f >> 4, c4 = (f & 15) << 2;
            *(float4*)&As[r][c4] = *(const float4*)&Dm[(size_t)(d0 + r) * NATOM + i0 + c4];
            *(float4*)&Bs[r][c4] = *(const float4*)&Dm[(size_t)(d0 + r) * NATOM + j0 + c4];
        }
        __syncthreads();
        #pragma unroll
        for (int kk = 0; kk < 32; ++kk) {
            float4 a = *(float4*)&As[kk][ty << 2];
            float4 b = *(float4*)&Bs[kk][tx << 2];
            float av[4] = {a.x, a.y, a.z, a.w};
            float bv[4] = {b.x, b.y, b.z, b.w};
            #pragma unroll
            for (int r = 0; r < 4; ++r)
                #pragma unroll
                for (int c = 0; c < 4; ++c) acc[r][c] += av[r] * bv[c];
        }
        __syncthreads();
    }
    #pragma unroll
    for (int r = 0; r < 4; ++r) {
        int gi = i0 + (ty << 2) + r;
        float4 v;
        float* vp = (float*)&v;
        #pragma unroll
        for (int c = 0; c < 4; ++c) {
            int gj = j0 + (tx << 2) + c;
            vp[c] = acc[r][c] + ((gi == gj) ? DIAG_EPS : 0.0f);
        }
        *(float4*)&G[(size_t)gi * NATOM + j0 + (tx << 2)] = v;
    }
}

// ---------------- h_bar = X^T D ----------------
// 128x128 tile, BK=16, 256 threads, 8x8 micro-tile (2x2 blocks of 4x4,
// split at +64 to keep LDS reads <=2-way bank aliased).
__global__ __launch_bounds__(256) void hbar_kernel(const float* __restrict__ X,
                                                   const float* __restrict__ Dm,
                                                   float* __restrict__ H, int Bsz) {
    __shared__ float As[16][128];   // X tile (cols = batch)
    __shared__ float Bs[16][128];   // D tile (cols = atoms)
    const int tid = threadIdx.x;
    const int tx = tid & 15, ty = tid >> 4;
    const int i0 = blockIdx.x * 128;  // batch
    const int j0 = blockIdx.y * 128;  // atom
    float acc[8][8] = {};
    for (int d0 = 0; d0 < DIM; d0 += 16) {
        #pragma unroll
        for (int l = 0; l < 2; ++l) {
            int f = tid + l * 256;          // 512 float4 per tile
            int r = f >> 5, c4 = (f & 31) << 2;
            *(float4*)&As[r][c4] = *(const float4*)&X[(size_t)(d0 + r) * Bsz + i0 + c4];
            *(float4*)&Bs[r][c4] = *(const float4*)&Dm[(size_t)(d0 + r) * NATOM + j0 + c4];
        }
        __syncthreads();
        #pragma unroll
        for (int kk = 0; kk < 16; ++kk) {
            float4 a0 = *(float4*)&As[kk][ty << 2];
            float4 a1 = *(float4*)&As[kk][64 + (ty << 2)];
            float4 b0 = *(float4*)&Bs[kk][tx << 2];
            float4 b1 = *(float4*)&Bs[kk][64 + (tx << 2)];
            float av[8] = {a0.x, a0.y, a0.z, a0.w, a1.x, a1.y, a1.z, a1.w};
            float bv[8] = {b0.x, b0.y, b0.z, b0.w, b1.x, b1.y, b1.z, b1.w};
            #pragma unroll
            for (int r = 0; r < 8; ++r)
                #pragma unroll
                for (int c = 0; c < 8; ++c) acc[r][c] += av[r] * bv[c];
        }
        __syncthreads();
    }
    #pragma unroll
    for (int ri = 0; ri < 2; ++ri)
        #pragma unroll
        for (int r = 0; r < 4; ++r) {
            int gi = i0 + ri * 64 + (ty << 2) + r;
            #pragma unroll
            for (int ci = 0; ci < 2; ++ci) {
                float4 v = make_float4(acc[ri * 4 + r][ci * 4 + 0], acc[ri * 4 + r][ci * 4 + 1],
                                       acc[ri * 4 + r][ci * 4 + 2], acc[ri * 4 + r][ci * 4 + 3]);
                *(float4*)&H[(size_t)gi * NATOM + j0 + ci * 64 + (tx << 2)] = v;
            }
        }
}

// ---------------- OMP iterations: one block per batch item ----------------
// Selected G rows staged in LDS (loaded once each); h computed on the fly
// inside the argmax pass (h's only consumer), so no h array and no separate
// update pass. 3 barriers per step.
__global__ __launch_bounds__(256) void omp_kernel(const float* __restrict__ hbar,
                                                  const float* __restrict__ G,
                                                  float* __restrict__ outI,
                                                  float* __restrict__ outC) {
    const int b = blockIdx.x;
    const int tid = threadIdx.x;
    __shared__ float hb[NATOM];            // original h_bar row (4 KB)
    __shared__ float rows[SPAR][NATOM];    // selected G rows (32 KB)
    __shared__ float sL[SPAR][SPAR];
    __shared__ float rv[4];
    __shared__ int   ri[4];
    __shared__ float sc[SPAR];
    __shared__ int   sI[SPAR];

    const int n0 = tid << 2;
    *(float4*)&hb[n0] = *(const float4*)&hbar[(size_t)b * NATOM + n0];
    __syncthreads();

    for (int s = 0; s < SPAR; ++s) {
        // --- h on the fly + masked argmax (first-occurrence tie-break) ---
        float4 hv = *(float4*)&hb[n0];
        float hvv[4] = {hv.x, hv.y, hv.z, hv.w};
        for (int j = 0; j < s; ++j) {
            float cj = sc[j];
            float4 g = *(float4*)&rows[j][n0];
            hvv[0] -= cj * g.x; hvv[1] -= cj * g.y;
            hvv[2] -= cj * g.z; hvv[3] -= cj * g.w;
        }
        float bestV = -2.0f; int bestN = 0;
        #pragma unroll
        for (int q = 0; q < 4; ++q) {
            int n = n0 + q;
            float v = fabsf(n2nf(hvv[q]));
            bool masked = false;
            for (int j = 0; j < s; ++j) masked |= (sI[j] == n);
            if (masked) v = -1.0f;
            if (v > bestV) { bestV = v; bestN = n; }   // ascending n: keeps first max
        }
        #pragma unroll
        for (int off = 32; off; off >>= 1) {
            float ov = __shfl_down(bestV, off);
            int   on = __shfl_down(bestN, off);
            if (ov > bestV || (ov == bestV && on < bestN)) { bestV = ov; bestN = on; }
        }
        if ((tid & 63) == 0) { rv[tid >> 6] = bestV; ri[tid >> 6] = bestN; }
        __syncthreads();

        // all threads compute the final winner redundantly (no extra barrier)
        float bv = rv[0]; int idx = ri[0];
        #pragma unroll
        for (int w = 1; w < 4; ++w)
            if (rv[w] > bv || (rv[w] == bv && ri[w] < idx)) { bv = rv[w]; idx = ri[w]; }
        if (tid == 0) sI[s] = idx;

        // --- stage G[idx] row into LDS (coalesced 4 KB, L2-resident) ---
        *(float4*)&rows[s][n0] = *(const float4*)&G[(size_t)idx * NATOM + n0];
        __syncthreads();

        // --- Cholesky rank-1 extension + cho_solve (tiny, serial) ---
        if (tid == 0) {
            float diag_g = rows[s][idx];               // G[idx][idx]
            if (s == 0) {
                sL[0][0] = sqrtf(fmaxf(diag_g, CHOL_EPS));
            } else {
                float ssum = 0.0f;
                for (int i = 0; i < s; ++i) {
                    float t = rows[i][idx];            // G[sI[i]][idx]
                    for (int j = 0; j < i; ++j) t -= sL[i][j] * sL[s][j];
                    float w = t / sL[i][i];
                    sL[s][i] = w;
                    ssum += w * w;
                }
                sL[s][s] = sqrtf(fmaxf(diag_g - ssum, CHOL_EPS));
            }
            float y[SPAR], c[SPAR];
            for (int i = 0; i <= s; ++i) {
                float t = hb[sI[i]];
                for (int j = 0; j < i; ++j) t -= sL[i][j] * y[j];
                y[i] = t / sL[i][i];
            }
            for (int i = s; i >= 0; --i) {
                float t = y[i];
                for (int j = i + 1; j <= s; ++j) t -= sL[j][i] * c[j];
                c[i] = t / sL[i][i];
            }
            for (int i = 0; i <= s; ++i) sc[i] = n2nf(c[i]);
        }
        __syncthreads();
    }

    if (tid < SPAR) {
        outI[(size_t)b * SPAR + tid] = (float)sI[tid];
        outC[(size_t)b * SPAR + tid] = sc[tid];
    }
}

extern "C" void kernel_launch(void* const* d_in, const int* in_sizes, int n_in,
                              void* d_out, int out_size, void* d_ws, size_t ws_size,
                              hipStream_t stream) {
    const float* X  = (const float*)d_in[0];   // [1024, B]
    const float* Dm = (const float*)d_in[1];   // [1024, 1024]
    const int Bsz = in_sizes[0] / DIM;         // 8192

    float* G    = (float*)d_ws;                         // 1024*1024
    float* hbar = (float*)d_ws + (size_t)NATOM * NATOM; // B*1024

    float* outI = (float*)d_out;
    float* outC = (float*)d_out + (size_t)Bsz * SPAR;

    gram_kernel<<<dim3(NATOM / 64, NATOM / 64), 256, 0, stream>>>(Dm, G);
    hbar_kernel<<<dim3(Bsz / 128, NATOM / 128), 256, 0, stream>>>(X, Dm, hbar, Bsz);
    omp_kernel<<<Bsz, 256, 0, stream>>>(hbar, G, outI, outC);
}

// Round 4
// 420.492 us; speedup vs baseline: 1.7437x; 1.7437x over previous
//
#include <hip/hip_runtime.h>
#include <math.h>

// Batched Cholesky-OMP. X: [1024, B] f32, D: [1024, 1024] f32.
// out: [B*8] indices-as-float, then [B*8] coeffs.
// ws: G (1024*1024 f32) @ 0, h_bar (B*1024 f32) after it.

#define DIM    1024
#define NATOM  1024
#define SPAR   8
#define DIAG_EPS 1e-4f
#define CHOL_EPS 1e-6f

__device__ __forceinline__ float n2nf(float x) {
    return isfinite(x) ? x : 0.0f;
}

// ---------------- G = D^T D + eps*I ----------------
// 64x64 tile, BK=32, 256 threads, 4x4 micro-tile.
__global__ __launch_bounds__(256) void gram_kernel(const float* __restrict__ Dm,
                                                   float* __restrict__ G) {
    __shared__ float As[32][64];
    __shared__ float Bs[32][64];
    const int tid = threadIdx.x;
    const int tx = tid & 15, ty = tid >> 4;
    const int i0 = blockIdx.x * 64, j0 = blockIdx.y * 64;
    float acc[4][4] = {};
    for (int d0 = 0; d0 < DIM; d0 += 32) {
        #pragma unroll
        for (int l = 0; l < 2; ++l) {
            int f = tid + l * 256;          // 512 float4 per tile
            int r = f >> 4, c4 = (f & 15) << 2;
            *(float4*)&As[r][c4] = *(const float4*)&Dm[(size_t)(d0 + r) * NATOM + i0 + c4];
            *(float4*)&Bs[r][c4] = *(const float4*)&Dm[(size_t)(d0 + r) * NATOM + j0 + c4];
        }
        __syncthreads();
        #pragma unroll
        for (int kk = 0; kk < 32; ++kk) {
            float4 a = *(float4*)&As[kk][ty << 2];
            float4 b = *(float4*)&Bs[kk][tx << 2];
            float av[4] = {a.x, a.y, a.z, a.w};
            float bv[4] = {b.x, b.y, b.z, b.w};
            #pragma unroll
            for (int r = 0; r < 4; ++r)
                #pragma unroll
                for (int c = 0; c < 4; ++c) acc[r][c] += av[r] * bv[c];
        }
        __syncthreads();
    }
    #pragma unroll
    for (int r = 0; r < 4; ++r) {
        int gi = i0 + (ty << 2) + r;
        float4 v;
        float* vp = (float*)&v;
        #pragma unroll
        for (int c = 0; c < 4; ++c) {
            int gj = j0 + (tx << 2) + c;
            vp[c] = acc[r][c] + ((gi == gj) ? DIAG_EPS : 0.0f);
        }
        *(float4*)&G[(size_t)gi * NATOM + j0 + (tx << 2)] = v;
    }
}

// ---------------- h_bar = X^T D ----------------
// 128x128 tile, BK=16, 256 threads, 8x8 micro-tile (2x2 blocks of 4x4,
// split at +64 to keep LDS reads <=2-way bank aliased).
__global__ __launch_bounds__(256) void hbar_kernel(const float* __restrict__ X,
                                                   const float* __restrict__ Dm,
                                                   float* __restrict__ H, int Bsz) {
    __shared__ float As[16][128];   // X tile (cols = batch)
    __shared__ float Bs[16][128];   // D tile (cols = atoms)
    const int tid = threadIdx.x;
    const int tx = tid & 15, ty = tid >> 4;
    const int i0 = blockIdx.x * 128;  // batch
    const int j0 = blockIdx.y * 128;  // atom
    float acc[8][8] = {};
    for (int d0 = 0; d0 < DIM; d0 += 16) {
        #pragma unroll
        for (int l = 0; l < 2; ++l) {
            int f = tid + l * 256;          // 512 float4 per tile
            int r = f >> 5, c4 = (f & 31) << 2;
            *(float4*)&As[r][c4] = *(const float4*)&X[(size_t)(d0 + r) * Bsz + i0 + c4];
            *(float4*)&Bs[r][c4] = *(const float4*)&Dm[(size_t)(d0 + r) * NATOM + j0 + c4];
        }
        __syncthreads();
        #pragma unroll
        for (int kk = 0; kk < 16; ++kk) {
            float4 a0 = *(float4*)&As[kk][ty << 2];
            float4 a1 = *(float4*)&As[kk][64 + (ty << 2)];
            float4 b0 = *(float4*)&Bs[kk][tx << 2];
            float4 b1 = *(float4*)&Bs[kk][64 + (tx << 2)];
            float av[8] = {a0.x, a0.y, a0.z, a0.w, a1.x, a1.y, a1.z, a1.w};
            float bv[8] = {b0.x, b0.y, b0.z, b0.w, b1.x, b1.y, b1.z, b1.w};
            #pragma unroll
            for (int r = 0; r < 8; ++r)
                #pragma unroll
                for (int c = 0; c < 8; ++c) acc[r][c] += av[r] * bv[c];
        }
        __syncthreads();
    }
    #pragma unroll
    for (int ri = 0; ri < 2; ++ri)
        #pragma unroll
        for (int r = 0; r < 4; ++r) {
            int gi = i0 + ri * 64 + (ty << 2) + r;
            #pragma unroll
            for (int ci = 0; ci < 2; ++ci) {
                float4 v = make_float4(acc[ri * 4 + r][ci * 4 + 0], acc[ri * 4 + r][ci * 4 + 1],
                                       acc[ri * 4 + r][ci * 4 + 2], acc[ri * 4 + r][ci * 4 + 3]);
                *(float4*)&H[(size_t)gi * NATOM + j0 + ci * 64 + (tx << 2)] = v;
            }
        }
}

// ---------------- OMP: one WAVE per batch item, register-resident ----------------
// No __syncthreads, no LDS. Step loop fully unrolled so every local array
// index is compile-time (registers, not scratch — rule #20). Cholesky/solves
// computed redundantly on all 64 lanes from uniform (broadcast) loads.
// Element layout: n(q) = q*256 + lane*4 + e  (perfectly coalesced float4 loads).
__global__ __launch_bounds__(64) void omp_kernel(const float* __restrict__ hbar,
                                                 const float* __restrict__ G,
                                                 float* __restrict__ outI,
                                                 float* __restrict__ outC) {
    const int b = blockIdx.x;
    const int lane = threadIdx.x;
    const float* hrow = hbar + (size_t)b * NATOM;

    float4 hb4[4];
    #pragma unroll
    for (int q = 0; q < 4; ++q)
        hb4[q] = *(const float4*)&hrow[q * 256 + lane * 4];

    unsigned mask16 = 0;      // bit (q*4+e) = my slot masked
    float L[SPAR][SPAR];      // registers (all indices compile-time)
    float invd[SPAR];
    float c[SPAR];
    float hsel[SPAR];
    int   sI[SPAR];

    #pragma unroll
    for (int s = 0; s < SPAR; ++s) {
        // --- h on the fly + masked argmax over my 16 slots ---
        float bestV = -2.0f; int bestN = 0;
        #pragma unroll
        for (int q = 0; q < 4; ++q) {
            float hv[4] = {hb4[q].x, hb4[q].y, hb4[q].z, hb4[q].w};
            #pragma unroll
            for (int j = 0; j < s; ++j) {
                const float4 g = *(const float4*)&G[(size_t)sI[j] * NATOM + q * 256 + lane * 4];
                hv[0] -= c[j] * g.x; hv[1] -= c[j] * g.y;
                hv[2] -= c[j] * g.z; hv[3] -= c[j] * g.w;
            }
            #pragma unroll
            for (int e = 0; e < 4; ++e) {
                float v = fabsf(n2nf(hv[e]));
                if ((mask16 >> (q * 4 + e)) & 1) v = -1.0f;
                int n = q * 256 + lane * 4 + e;
                if (v > bestV) { bestV = v; bestN = n; }   // n ascending: keeps first max
            }
        }
        // --- 64-lane butterfly reduce (max, tie -> smaller n) ---
        #pragma unroll
        for (int off = 1; off < 64; off <<= 1) {
            float ov = __shfl_xor(bestV, off);
            int   on = __shfl_xor(bestN, off);
            if (ov > bestV || (ov == bestV && on < bestN)) { bestV = ov; bestN = on; }
        }
        const int idx = bestN;             // uniform across wave
        sI[s] = idx;
        if (((idx >> 2) & 63) == lane)
            mask16 |= 1u << (((idx >> 8) << 2) | (idx & 3));

        // --- uniform gathers: G column at idx, diag, hb[idx] (HW broadcast) ---
        float diag = G[(size_t)idx * NATOM + idx];
        float gcol[SPAR];
        #pragma unroll
        for (int i = 0; i < s; ++i) gcol[i] = G[(size_t)sI[i] * NATOM + idx];
        hsel[s] = hrow[idx];

        // --- Cholesky extension (all lanes redundantly, pure registers) ---
        if (s == 0) {
            L[0][0] = sqrtf(fmaxf(diag, CHOL_EPS));
            invd[0] = 1.0f / L[0][0];
        } else {
            float ss = 0.0f;
            #pragma unroll
            for (int i = 0; i < s; ++i) {
                float t = gcol[i];
                #pragma unroll
                for (int j = 0; j < i; ++j) t -= L[i][j] * L[s][j];
                float w = t * invd[i];
                L[s][i] = w;
                ss += w * w;
            }
            L[s][s] = sqrtf(fmaxf(diag - ss, CHOL_EPS));
            invd[s] = 1.0f / L[s][s];
        }

        // --- cho_solve: L y = hsel ; L^T c = y ---
        float y[SPAR];
        #pragma unroll
        for (int i = 0; i <= s; ++i) {
            float t = hsel[i];
            #pragma unroll
            for (int j = 0; j < i; ++j) t -= L[i][j] * y[j];
            y[i] = t * invd[i];
        }
        #pragma unroll
        for (int i = s; i >= 0; --i) {
            float t = y[i];
            #pragma unroll
            for (int j = i + 1; j <= s; ++j) t -= L[j][i] * c[j];
            c[i] = n2nf(t * invd[i]);
        }
    }

    if (lane == 0) {
        #pragma unroll
        for (int i = 0; i < SPAR; ++i) {
            outI[(size_t)b * SPAR + i] = (float)sI[i];
            outC[(size_t)b * SPAR + i] = c[i];
        }
    }
}

extern "C" void kernel_launch(void* const* d_in, const int* in_sizes, int n_in,
                              void* d_out, int out_size, void* d_ws, size_t ws_size,
                              hipStream_t stream) {
    const float* X  = (const float*)d_in[0];   // [1024, B]
    const float* Dm = (const float*)d_in[1];   // [1024, 1024]
    const int Bsz = in_sizes[0] / DIM;         // 8192

    float* G    = (float*)d_ws;                         // 1024*1024
    float* hbar = (float*)d_ws + (size_t)NATOM * NATOM; // B*1024

    float* outI = (float*)d_out;
    float* outC = (float*)d_out + (size_t)Bsz * SPAR;

    gram_kernel<<<dim3(NATOM / 64, NATOM / 64), 256, 0, stream>>>(Dm, G);
    hbar_kernel<<<dim3(Bsz / 128, NATOM / 128), 256, 0, stream>>>(X, Dm, hbar, Bsz);
    omp_kernel<<<Bsz, 64, 0, stream>>>(hbar, G, outI, outC);
}

// Round 7
// 325.767 us; speedup vs baseline: 2.2507x; 1.2908x over previous
//
#include <hip/hip_runtime.h>
#include <math.h>

// Batched Cholesky-OMP. X: [1024, B] f32, D: [1024, 1024] f32.
// out: [B*8] indices-as-float, then [B*8] coeffs.

#define DIM    1024
#define NATOM  1024
#define SPAR   8
#define DIAG_EPS 1e-4f
#define CHOL_EPS 1e-6f
#define LO_SCALE   2048.0f          // 2^11: keeps fp16 residuals in normal range
#define LO_INV     4.8828125e-4f    // 2^-11 exact

typedef __attribute__((ext_vector_type(8))) _Float16 half8;
typedef __attribute__((ext_vector_type(4))) _Float16 half4;
typedef __attribute__((ext_vector_type(4))) float floatx4;

__device__ __forceinline__ float n2nf(float x) {
    return isfinite(x) ? x : 0.0f;
}

// ---------------- G = D^T D + eps*I (unchanged, measured-correct) ----------------
__global__ __launch_bounds__(256) void gram_kernel(const float* __restrict__ Dm,
                                                   float* __restrict__ G) {
    __shared__ float As[32][64];
    __shared__ float Bs[32][64];
    const int tid = threadIdx.x;
    const int tx = tid & 15, ty = tid >> 4;
    const int i0 = blockIdx.x * 64, j0 = blockIdx.y * 64;
    float acc[4][4] = {};
    for (int d0 = 0; d0 < DIM; d0 += 32) {
        #pragma unroll
        for (int l = 0; l < 2; ++l) {
            int f = tid + l * 256;
            int r = f >> 4, c4 = (f & 15) << 2;
            *(float4*)&As[r][c4] = *(const float4*)&Dm[(size_t)(d0 + r) * NATOM + i0 + c4];
            *(float4*)&Bs[r][c4] = *(const float4*)&Dm[(size_t)(d0 + r) * NATOM + j0 + c4];
        }
        __syncthreads();
        #pragma unroll
        for (int kk = 0; kk < 32; ++kk) {
            float4 a = *(float4*)&As[kk][ty << 2];
            float4 b = *(float4*)&Bs[kk][tx << 2];
            float av[4] = {a.x, a.y, a.z, a.w};
            float bv[4] = {b.x, b.y, b.z, b.w};
            #pragma unroll
            for (int r = 0; r < 4; ++r)
                #pragma unroll
                for (int c = 0; c < 4; ++c) acc[r][c] += av[r] * bv[c];
        }
        __syncthreads();
    }
    #pragma unroll
    for (int r = 0; r < 4; ++r) {
        int gi = i0 + (ty << 2) + r;
        float4 v;
        float* vp = (float*)&v;
        #pragma unroll
        for (int c = 0; c < 4; ++c) {
            int gj = j0 + (tx << 2) + c;
            vp[c] = acc[r][c] + ((gi == gj) ? DIAG_EPS : 0.0f);
        }
        *(float4*)&G[(size_t)gi * NATOM + j0 + (tx << 2)] = v;
    }
}

// ---------------- transpose + fp16 hi/lo split (lo scaled by 2^11) ----------------
// src [DIM][cols] f32 -> dstH/dstL [cols][DIM] fp16 (transposed).
// dstL = fp16((x - fp16(x)) * 2048): O(1) values, no denormal flush.
__global__ __launch_bounds__(256) void split_kernel(const float* __restrict__ src, int cols,
                                                    _Float16* __restrict__ dstH,
                                                    _Float16* __restrict__ dstL) {
    __shared__ float tile[64][65];   // pitch 65: column reads ~conflict-free
    const int t = threadIdx.x;
    const int c0 = blockIdx.x * 64;  // col block (batch/atom)
    const int d0 = blockIdx.y * 64;  // row block (dim)
    #pragma unroll
    for (int v = 0; v < 4; ++v) {
        int row = (t >> 4) + (v << 4);
        int col4 = (t & 15) << 2;
        *(float4*)&tile[row][col4] = *(const float4*)&src[(size_t)(d0 + row) * cols + c0 + col4];
    }
    __syncthreads();
    #pragma unroll
    for (int v = 0; v < 4; ++v) {
        int c  = (t >> 4) + (v << 4);   // output row = src col
        int d4 = (t & 15) << 2;         // output col = src row (dim)
        float x0 = tile[d4 + 0][c], x1 = tile[d4 + 1][c];
        float x2 = tile[d4 + 2][c], x3 = tile[d4 + 3][c];
        _Float16 h0 = (_Float16)x0, h1 = (_Float16)x1, h2 = (_Float16)x2, h3 = (_Float16)x3;
        half4 hv = {h0, h1, h2, h3};
        half4 lv = {(_Float16)((x0 - (float)h0) * LO_SCALE),
                    (_Float16)((x1 - (float)h1) * LO_SCALE),
                    (_Float16)((x2 - (float)h2) * LO_SCALE),
                    (_Float16)((x3 - (float)h3) * LO_SCALE)};
        *(half4*)&dstH[(size_t)(c0 + c) * DIM + d0 + d4] = hv;
        *(half4*)&dstL[(size_t)(c0 + c) * DIM + d0 + d4] = lv;
    }
}

// ---------------- h_bar = X^T D via 3-term fp16 MFMA, scaled-residual ----------------
// H = Xh.Dh + 2^-11*(Xh.Dl' + Xl'.Dh), separate fp32 accumulators per scale.
// Operands pre-transposed k-contiguous. 128x128 tile, BK=32, 4 waves (2x2).
#define LPITCH 40   // 32 + 8 pad halves
__global__ __launch_bounds__(256) void hbar2_kernel(const _Float16* __restrict__ Xh,
                                                    const _Float16* __restrict__ Xl,
                                                    const _Float16* __restrict__ Dh,
                                                    const _Float16* __restrict__ Dl,
                                                    float* __restrict__ H) {
    __shared__ _Float16 As[2][128 * LPITCH];   // [plane hi/lo][row*LPITCH+k]
    __shared__ _Float16 Bs[2][128 * LPITCH];
    const int tid = threadIdx.x;
    const int lane = tid & 63;
    const int w = tid >> 6;
    const int wm = w >> 1, wn = w & 1;
    const int i0 = blockIdx.x * 128;   // batch
    const int n0 = blockIdx.y * 128;   // atom
    const int l15 = lane & 15, lg = lane >> 4;

    floatx4 acc_hh[4][4] = {};   // scale 1
    floatx4 acc_md[4][4] = {};   // scale 2^-11

    for (int d0 = 0; d0 < DIM; d0 += 32) {
        #pragma unroll
        for (int v = 0; v < 4; ++v) {
            int idx = tid + (v << 8);
            int plane = idx >> 9;
            int rem = idx & 511;
            int row = rem >> 2;
            int seg = (rem & 3) << 3;
            const _Float16* sa = plane ? Xl : Xh;
            const _Float16* sb = plane ? Dl : Dh;
            half8 av = *(const half8*)&sa[(size_t)(i0 + row) * DIM + d0 + seg];
            half8 bv = *(const half8*)&sb[(size_t)(n0 + row) * DIM + d0 + seg];
            *(half8*)&As[plane][row * LPITCH + seg] = av;
            *(half8*)&Bs[plane][row * LPITCH + seg] = bv;
        }
        __syncthreads();

        half8 bf[4][2];
        #pragma unroll
        for (int fn = 0; fn < 4; ++fn)
            #pragma unroll
            for (int p = 0; p < 2; ++p)
                bf[fn][p] = *(half8*)&Bs[p][(wn * 64 + fn * 16 + l15) * LPITCH + (lg << 3)];
        #pragma unroll
        for (int fm = 0; fm < 4; ++fm) {
            half8 ah = *(half8*)&As[0][(wm * 64 + fm * 16 + l15) * LPITCH + (lg << 3)];
            half8 al = *(half8*)&As[1][(wm * 64 + fm * 16 + l15) * LPITCH + (lg << 3)];
            #pragma unroll
            for (int fn = 0; fn < 4; ++fn) {
                acc_hh[fm][fn] = __builtin_amdgcn_mfma_f32_16x16x32_f16(ah, bf[fn][0], acc_hh[fm][fn], 0, 0, 0);
                acc_md[fm][fn] = __builtin_amdgcn_mfma_f32_16x16x32_f16(ah, bf[fn][1], acc_md[fm][fn], 0, 0, 0);
                acc_md[fm][fn] = __builtin_amdgcn_mfma_f32_16x16x32_f16(al, bf[fn][0], acc_md[fm][fn], 0, 0, 0);
            }
        }
        __syncthreads();
    }

    // epilogue: C/D layout col=lane&15, row=(lane>>4)*4+reg (m89-verified)
    #pragma unroll
    for (int fm = 0; fm < 4; ++fm)
        #pragma unroll
        for (int r = 0; r < 4; ++r) {
            int row = i0 + wm * 64 + fm * 16 + (lg << 2) + r;
            #pragma unroll
            for (int fn = 0; fn < 4; ++fn) {
                int col = n0 + wn * 64 + fn * 16 + l15;
                H[(size_t)row * NATOM + col] = acc_hh[fm][fn][r] + LO_INV * acc_md[fm][fn][r];
            }
        }
}

// ---------------- fallback fp32 h_bar (round-4 measured-correct) ----------------
__global__ __launch_bounds__(256) void hbar_kernel(const float* __restrict__ X,
                                                   const float* __restrict__ Dm,
                                                   float* __restrict__ H, int Bsz) {
    __shared__ float As[16][128];
    __shared__ float Bs[16][128];
    const int tid = threadIdx.x;
    const int tx = tid & 15, ty = tid >> 4;
    const int i0 = blockIdx.x * 128;
    const int j0 = blockIdx.y * 128;
    float acc[8][8] = {};
    for (int d0 = 0; d0 < DIM; d0 += 16) {
        #pragma unroll
        for (int l = 0; l < 2; ++l) {
            int f = tid + l * 256;
            int r = f >> 5, c4 = (f & 31) << 2;
            *(float4*)&As[r][c4] = *(const float4*)&X[(size_t)(d0 + r) * Bsz + i0 + c4];
            *(float4*)&Bs[r][c4] = *(const float4*)&Dm[(size_t)(d0 + r) * NATOM + j0 + c4];
        }
        __syncthreads();
        #pragma unroll
        for (int kk = 0; kk < 16; ++kk) {
            float4 a0 = *(float4*)&As[kk][ty << 2];
            float4 a1 = *(float4*)&As[kk][64 + (ty << 2)];
            float4 b0 = *(float4*)&Bs[kk][tx << 2];
            float4 b1 = *(float4*)&Bs[kk][64 + (tx << 2)];
            float av[8] = {a0.x, a0.y, a0.z, a0.w, a1.x, a1.y, a1.z, a1.w};
            float bv[8] = {b0.x, b0.y, b0.z, b0.w, b1.x, b1.y, b1.z, b1.w};
            #pragma unroll
            for (int r = 0; r < 8; ++r)
                #pragma unroll
                for (int c = 0; c < 8; ++c) acc[r][c] += av[r] * bv[c];
        }
        __syncthreads();
    }
    #pragma unroll
    for (int ri = 0; ri < 2; ++ri)
        #pragma unroll
        for (int r = 0; r < 4; ++r) {
            int gi = i0 + ri * 64 + (ty << 2) + r;
            #pragma unroll
            for (int ci = 0; ci < 2; ++ci) {
                float4 v = make_float4(acc[ri * 4 + r][ci * 4 + 0], acc[ri * 4 + r][ci * 4 + 1],
                                       acc[ri * 4 + r][ci * 4 + 2], acc[ri * 4 + r][ci * 4 + 3]);
                *(float4*)&H[(size_t)gi * NATOM + j0 + ci * 64 + (tx << 2)] = v;
            }
        }
}

// ---------------- OMP: one WAVE per batch item (unchanged, measured-correct) ----------------
__global__ __launch_bounds__(64) void omp_kernel(const float* __restrict__ hbar,
                                                 const float* __restrict__ G,
                                                 float* __restrict__ outI,
                                                 float* __restrict__ outC) {
    const int b = blockIdx.x;
    const int lane = threadIdx.x;
    const float* hrow = hbar + (size_t)b * NATOM;

    float4 hb4[4];
    #pragma unroll
    for (int q = 0; q < 4; ++q)
        hb4[q] = *(const float4*)&hrow[q * 256 + lane * 4];

    unsigned mask16 = 0;
    float L[SPAR][SPAR];
    float invd[SPAR];
    float c[SPAR];
    float hsel[SPAR];
    int   sI[SPAR];

    #pragma unroll
    for (int s = 0; s < SPAR; ++s) {
        float bestV = -2.0f; int bestN = 0;
        #pragma unroll
        for (int q = 0; q < 4; ++q) {
            float hv[4] = {hb4[q].x, hb4[q].y, hb4[q].z, hb4[q].w};
            #pragma unroll
            for (int j = 0; j < s; ++j) {
                const float4 g = *(const float4*)&G[(size_t)sI[j] * NATOM + q * 256 + lane * 4];
                hv[0] -= c[j] * g.x; hv[1] -= c[j] * g.y;
                hv[2] -= c[j] * g.z; hv[3] -= c[j] * g.w;
            }
            #pragma unroll
            for (int e = 0; e < 4; ++e) {
                float v = fabsf(n2nf(hv[e]));
                if ((mask16 >> (q * 4 + e)) & 1) v = -1.0f;
                int n = q * 256 + lane * 4 + e;
                if (v > bestV) { bestV = v; bestN = n; }
            }
        }
        #pragma unroll
        for (int off = 1; off < 64; off <<= 1) {
            float ov = __shfl_xor(bestV, off);
            int   on = __shfl_xor(bestN, off);
            if (ov > bestV || (ov == bestV && on < bestN)) { bestV = ov; bestN = on; }
        }
        const int idx = bestN;
        sI[s] = idx;
        if (((idx >> 2) & 63) == lane)
            mask16 |= 1u << (((idx >> 8) << 2) | (idx & 3));

        float diag = G[(size_t)idx * NATOM + idx];
        float gcol[SPAR];
        #pragma unroll
        for (int i = 0; i < s; ++i) gcol[i] = G[(size_t)sI[i] * NATOM + idx];
        hsel[s] = hrow[idx];

        if (s == 0) {
            L[0][0] = sqrtf(fmaxf(diag, CHOL_EPS));
            invd[0] = 1.0f / L[0][0];
        } else {
            float ss = 0.0f;
            #pragma unroll
            for (int i = 0; i < s; ++i) {
                float t = gcol[i];
                #pragma unroll
                for (int j = 0; j < i; ++j) t -= L[i][j] * L[s][j];
                float w = t * invd[i];
                L[s][i] = w;
                ss += w * w;
            }
            L[s][s] = sqrtf(fmaxf(diag - ss, CHOL_EPS));
            invd[s] = 1.0f / L[s][s];
        }

        float y[SPAR];
        #pragma unroll
        for (int i = 0; i <= s; ++i) {
            float t = hsel[i];
            #pragma unroll
            for (int j = 0; j < i; ++j) t -= L[i][j] * y[j];
            y[i] = t * invd[i];
        }
        #pragma unroll
        for (int i = s; i >= 0; --i) {
            float t = y[i];
            #pragma unroll
            for (int j = i + 1; j <= s; ++j) t -= L[j][i] * c[j];
            c[i] = n2nf(t * invd[i]);
        }
    }

    if (lane == 0) {
        #pragma unroll
        for (int i = 0; i < SPAR; ++i) {
            outI[(size_t)b * SPAR + i] = (float)sI[i];
            outC[(size_t)b * SPAR + i] = c[i];
        }
    }
}

extern "C" void kernel_launch(void* const* d_in, const int* in_sizes, int n_in,
                              void* d_out, int out_size, void* d_ws, size_t ws_size,
                              hipStream_t stream) {
    const float* X  = (const float*)d_in[0];   // [1024, B]
    const float* Dm = (const float*)d_in[1];   // [1024, 1024]
    const int Bsz = in_sizes[0] / DIM;         // 8192

    float* G    = (float*)d_ws;
    float* hbar = G + (size_t)NATOM * NATOM;
    char* p = (char*)(hbar + (size_t)Bsz * NATOM);
    _Float16* XhT = (_Float16*)p;
    _Float16* XlT = XhT + (size_t)Bsz * DIM;
    _Float16* DhT = XlT + (size_t)Bsz * DIM;
    _Float16* DlT = DhT + (size_t)NATOM * DIM;
    size_t need = (size_t)((char*)(DlT + (size_t)NATOM * DIM) - (char*)d_ws);

    float* outI = (float*)d_out;
    float* outC = (float*)d_out + (size_t)Bsz * SPAR;

    gram_kernel<<<dim3(NATOM / 64, NATOM / 64), 256, 0, stream>>>(Dm, G);

    if (ws_size >= need) {
        split_kernel<<<dim3(Bsz / 64, DIM / 64), 256, 0, stream>>>(X, Bsz, XhT, XlT);
        split_kernel<<<dim3(NATOM / 64, DIM / 64), 256, 0, stream>>>(Dm, NATOM, DhT, DlT);
        hbar2_kernel<<<dim3(Bsz / 128, NATOM / 128), 256, 0, stream>>>(XhT, XlT, DhT, DlT, hbar);
    } else {
        hbar_kernel<<<dim3(Bsz / 128, NATOM / 128), 256, 0, stream>>>(X, Dm, hbar, Bsz);
    }

    omp_kernel<<<Bsz, 64, 0, stream>>>(hbar, G, outI, outC);
}